// Round 1
// baseline (832.077 us; speedup 1.0000x reference)
//
#include <hip/hip_runtime.h>
#include <hip/hip_bf16.h>
#include <stdint.h>

// MoE: N=8192 tokens, D=2048, E=8 experts, top-2 routing.
// Pipeline: memset(cnt,out) -> cvt W,x to bf16 -> gate (fp32) -> grouped bf16 MFMA GEMM
//           with fused bias+ReLU+gate-weight and fp32 atomicAdd combine.

#define N_TOK 8192
#define DIM   2048
#define NEXP  8

#define BM 128
#define BN 128
#define BK 64

typedef __attribute__((ext_vector_type(8))) short short8;
typedef __attribute__((ext_vector_type(4))) float f32x4;

// ---- workspace layout (bytes) ----
#define OFF_CNT 0
#define OFF_TOK 1024
#define OFF_WL  (OFF_TOK + N_TOK*NEXP*4)
#define OFF_XB  (OFF_WL + N_TOK*NEXP*4)
#define OFF_WB  (OFF_XB + (size_t)N_TOK*DIM*2)
// total = OFF_WB + E*D*D*2 = ~101 MB

__device__ __forceinline__ void gload_lds16(const void* g, void* l) {
  __builtin_amdgcn_global_load_lds(
      (const __attribute__((address_space(1))) void*)g,
      (__attribute__((address_space(3))) void*)l, 16, 0, 0);
}

// ---------------- fp32 -> bf16 conversion (float4 vectorized) ----------------
__global__ __launch_bounds__(256) void cvt_kernel(const float* __restrict__ in,
                                                  __hip_bfloat16* __restrict__ out,
                                                  int n4) {
  int stride = gridDim.x * blockDim.x;
  for (int i = blockIdx.x * blockDim.x + threadIdx.x; i < n4; i += stride) {
    float4 v = reinterpret_cast<const float4*>(in)[i];
    union { ushort4 u; __hip_bfloat16 h[4]; } cv;
    cv.h[0] = __float2bfloat16(v.x);
    cv.h[1] = __float2bfloat16(v.y);
    cv.h[2] = __float2bfloat16(v.z);
    cv.h[3] = __float2bfloat16(v.w);
    reinterpret_cast<ushort4*>(out)[i] = cv.u;
  }
}

// ---------------- gating: one wave per token, fp32 exact-ish ----------------
__global__ __launch_bounds__(256) void gate_kernel(
    const float* __restrict__ x, const float* __restrict__ wg,
    const float* __restrict__ bg, int* __restrict__ cnt,
    int* __restrict__ toklist, float* __restrict__ wlist) {
  const int wave = threadIdx.x >> 6;
  const int lane = threadIdx.x & 63;
  const int t = blockIdx.x * 4 + wave;
  const float4* xr = reinterpret_cast<const float4*>(x + (size_t)t * DIM);
  float acc[NEXP];
#pragma unroll
  for (int e = 0; e < NEXP; ++e) acc[e] = 0.f;
#pragma unroll
  for (int j = 0; j < DIM / 4 / 64; ++j) {     // 8 iters
    float4 xv = xr[lane + 64 * j];
#pragma unroll
    for (int e = 0; e < NEXP; ++e) {
      float4 gv = reinterpret_cast<const float4*>(wg + (size_t)e * DIM)[lane + 64 * j];
      acc[e] += xv.x * gv.x + xv.y * gv.y + xv.z * gv.z + xv.w * gv.w;
    }
  }
#pragma unroll
  for (int e = 0; e < NEXP; ++e) {
    float v = acc[e];
#pragma unroll
    for (int off = 32; off > 0; off >>= 1) v += __shfl_down(v, off);
    acc[e] = v;
  }
  if (lane == 0) {
    float lg[NEXP];
#pragma unroll
    for (int e = 0; e < NEXP; ++e) lg[e] = acc[e] + bg[e];
    float m = lg[0];
#pragma unroll
    for (int e = 1; e < NEXP; ++e) m = fmaxf(m, lg[e]);
    float s = 0.f, w[NEXP];
#pragma unroll
    for (int e = 0; e < NEXP; ++e) { w[e] = expf(lg[e] - m); s += w[e]; }
    float inv = 1.f / s;
    // top-2 on logits (monotonic with softmax); ties -> lowest index (matches top_k)
    int i0 = 0;
#pragma unroll
    for (int e = 1; e < NEXP; ++e) if (lg[e] > lg[i0]) i0 = e;
    int i1 = -1;
#pragma unroll
    for (int e = 0; e < NEXP; ++e)
      if (e != i0 && (i1 < 0 || lg[e] > lg[i1])) i1 = e;
    int p0 = atomicAdd(&cnt[i0], 1);
    toklist[i0 * N_TOK + p0] = t;  wlist[i0 * N_TOK + p0] = w[i0] * inv;
    int p1 = atomicAdd(&cnt[i1], 1);
    toklist[i1 * N_TOK + p1] = t;  wlist[i1 * N_TOK + p1] = w[i1] * inv;
  }
}

// ---------------- grouped GEMM: C = relu(Xg @ We^T + be) * wt, atomicAdd to out ----
// grid.x = E * (N_TOK/BM); grid.y = DIM/BN. 256 threads = 4 waves, 2x2 wave grid,
// each wave 64x64 = 4x4 frags of 16x16x32 bf16 MFMA.
__global__ __launch_bounds__(256, 2) void moe_gemm(
    const __hip_bfloat16* __restrict__ xb, const __hip_bfloat16* __restrict__ wb,
    const float* __restrict__ be, const int* __restrict__ cnt,
    const int* __restrict__ toklist, const float* __restrict__ wlist,
    float* __restrict__ out) {
  const int e = blockIdx.x >> 6;          // / (N_TOK/BM)
  const int tr = blockIdx.x & 63;
  const int ce = cnt[e];
  const int row0 = tr * BM;
  if (row0 >= ce) return;                 // uniform early-exit
  const int bn0 = blockIdx.y * BN;

  __shared__ __align__(16) __hip_bfloat16 sX[BM * BK];
  __shared__ __align__(16) __hip_bfloat16 sW[BN * BK];
  __shared__ int   sTok[BM];
  __shared__ float sWt[BM];

  const int tid = threadIdx.x;
  if (tid < BM) {
    int r = row0 + tid;
    bool valid = r < ce;
    sTok[tid] = valid ? toklist[e * N_TOK + r] : 0;
    sWt[tid]  = valid ? wlist[e * N_TOK + r] : 0.f;
  }
  __syncthreads();

  // Staging sources. LDS dest is LINEAR (global_load_lds requirement, rule #21);
  // the XOR swizzle (g^(r&7), 16B granules within a 128B row) is applied by
  // permuting the GLOBAL source granule; reads apply the same XOR.
  const char* srcX[4];
  const char* srcW[4];
#pragma unroll
  for (int n = 0; n < 4; ++n) {
    int c = tid + 256 * n;    // 16B chunk id 0..1023
    int r = c >> 3;           // tile row 0..127
    int p = c & 7;            // physical granule
    int g = p ^ (r & 7);      // logical (source) granule
    srcX[n] = (const char*)(xb + (size_t)sTok[r] * DIM + g * 8);
    srcW[n] = (const char*)(wb + (size_t)(e * DIM + bn0 + r) * DIM + g * 8);
  }

  char* ldsX = (char*)sX;
  char* ldsW = (char*)sW;
  const int lane = tid & 63;
  const int wv = tid >> 6;
  const int wr = (wv >> 1) * 64;
  const int wc = (wv & 1) * 64;

  f32x4 acc[4][4];
#pragma unroll
  for (int mi = 0; mi < 4; ++mi)
#pragma unroll
    for (int ni = 0; ni < 4; ++ni)
      acc[mi][ni] = (f32x4){0.f, 0.f, 0.f, 0.f};

  for (int kt = 0; kt < DIM / BK; ++kt) {
#pragma unroll
    for (int n = 0; n < 4; ++n) {
      gload_lds16(srcX[n] + kt * (BK * 2), ldsX + (tid + 256 * n) * 16);
      gload_lds16(srcW[n] + kt * (BK * 2), ldsW + (tid + 256 * n) * 16);
    }
    __syncthreads();    // compiler drains vmcnt before s_barrier (m97 structure)
#pragma unroll
    for (int ks = 0; ks < 2; ++ks) {
      short8 af[4], bf[4];
      const int gbase = ks * 4 + (lane >> 4);
#pragma unroll
      for (int i = 0; i < 4; ++i) {
        int rA = wr + i * 16 + (lane & 15);
        af[i] = *(const short8*)(ldsX + rA * 128 + ((gbase ^ (rA & 7)) << 4));
        int rB = wc + i * 16 + (lane & 15);
        bf[i] = *(const short8*)(ldsW + rB * 128 + ((gbase ^ (rB & 7)) << 4));
      }
#pragma unroll
      for (int mi = 0; mi < 4; ++mi)
#pragma unroll
        for (int ni = 0; ni < 4; ++ni)
          acc[mi][ni] = __builtin_amdgcn_mfma_f32_16x16x32_bf16(
              af[mi], bf[ni], acc[mi][ni], 0, 0, 0);
    }
    __syncthreads();
  }

  // epilogue: bias + relu + gate-weight, accumulate into out (pre-zeroed).
  // C/D layout (m89-verified): col = lane&15, row = (lane>>4)*4 + reg.
  const int cvalid = ce - row0;
#pragma unroll
  for (int mi = 0; mi < 4; ++mi) {
    int lr0 = wr + mi * 16 + (lane >> 4) * 4;
#pragma unroll
    for (int ni = 0; ni < 4; ++ni) {
      int col = bn0 + wc + ni * 16 + (lane & 15);
      float bv = be[e * DIM + col];
#pragma unroll
      for (int q = 0; q < 4; ++q) {
        int lr = lr0 + q;
        if (lr < cvalid) {
          float v = acc[mi][ni][q] + bv;
          v = fmaxf(v, 0.f) * sWt[lr];
          atomicAdd(out + (size_t)sTok[lr] * DIM + col, v);
        }
      }
    }
  }
}

extern "C" void kernel_launch(void* const* d_in, const int* in_sizes, int n_in,
                              void* d_out, int out_size, void* d_ws, size_t ws_size,
                              hipStream_t stream) {
  const float* x  = (const float*)d_in[0];
  const float* We = (const float*)d_in[1];
  const float* be = (const float*)d_in[2];
  const float* Wg = (const float*)d_in[3];
  const float* bg = (const float*)d_in[4];
  float* out = (float*)d_out;
  char* ws = (char*)d_ws;

  int*   cnt = (int*)(ws + OFF_CNT);
  int*   tok = (int*)(ws + OFF_TOK);
  float* wl  = (float*)(ws + OFF_WL);
  __hip_bfloat16* xb = (__hip_bfloat16*)(ws + OFF_XB);
  __hip_bfloat16* wb = (__hip_bfloat16*)(ws + OFF_WB);

  hipMemsetAsync(cnt, 0, 1024, stream);
  hipMemsetAsync(out, 0, (size_t)N_TOK * DIM * sizeof(float), stream);

  cvt_kernel<<<2048, 256, 0, stream>>>(We, wb, NEXP * DIM * DIM / 4);
  cvt_kernel<<<1024, 256, 0, stream>>>(x, xb, N_TOK * DIM / 4);
  gate_kernel<<<N_TOK / 4, 256, 0, stream>>>(x, Wg, bg, cnt, tok, wl);

  dim3 grid(NEXP * (N_TOK / BM), DIM / BN);
  moe_gemm<<<grid, 256, 0, stream>>>(xb, wb, be, cnt, tok, wl, out);
}

// Round 2
// 795.016 us; speedup vs baseline: 1.0466x; 1.0466x over previous
//
#include <hip/hip_runtime.h>
#include <hip/hip_bf16.h>
#include <stdint.h>

// MoE: N=8192 tokens, D=2048, E=8 experts, top-2 routing.
// Pipeline: memset(cnt,out) -> gate (fp32, fused x->bf16 cast) -> cvt W ->
//           grouped bf16 MFMA GEMM (256x256, BK=64, 2-phase double-buffer)
//           with fused bias+ReLU+gate-weight and fp32 atomicAdd combine.

#define N_TOK 8192
#define DIM   2048
#define NEXP  8

#define BM 256
#define BN 256
#define BK 64
#define KT (DIM / BK)   // 32 K-steps

typedef __attribute__((ext_vector_type(8))) short short8;
typedef __attribute__((ext_vector_type(4))) float f32x4;

// ---- workspace layout (bytes) ----
#define OFF_CNT 0
#define OFF_TOK 1024
#define OFF_WL  (OFF_TOK + N_TOK*NEXP*4)
#define OFF_XB  (OFF_WL + N_TOK*NEXP*4)
#define OFF_WB  (OFF_XB + (size_t)N_TOK*DIM*2)
// total = OFF_WB + E*D*D*2 = ~101 MB

__device__ __forceinline__ void gload_lds16(const void* g, void* l) {
  __builtin_amdgcn_global_load_lds(
      (const __attribute__((address_space(1))) void*)g,
      (__attribute__((address_space(3))) void*)l, 16, 0, 0);
}

// ---------------- fp32 -> bf16 conversion for W (float4 vectorized) ----------------
__global__ __launch_bounds__(256) void cvt_kernel(const float* __restrict__ in,
                                                  __hip_bfloat16* __restrict__ out,
                                                  int n4) {
  int stride = gridDim.x * blockDim.x;
  for (int i = blockIdx.x * blockDim.x + threadIdx.x; i < n4; i += stride) {
    float4 v = reinterpret_cast<const float4*>(in)[i];
    union { ushort4 u; __hip_bfloat16 h[4]; } cv;
    cv.h[0] = __float2bfloat16(v.x);
    cv.h[1] = __float2bfloat16(v.y);
    cv.h[2] = __float2bfloat16(v.z);
    cv.h[3] = __float2bfloat16(v.w);
    reinterpret_cast<ushort4*>(out)[i] = cv.u;
  }
}

// ---------------- gating: one wave per token; also emits xb (bf16 cast of x) -------
__global__ __launch_bounds__(256) void gate_kernel(
    const float* __restrict__ x, const float* __restrict__ wg,
    const float* __restrict__ bg, __hip_bfloat16* __restrict__ xb,
    int* __restrict__ cnt, int* __restrict__ toklist, float* __restrict__ wlist) {
  const int wave = threadIdx.x >> 6;
  const int lane = threadIdx.x & 63;
  const int t = blockIdx.x * 4 + wave;
  const float4* xr = reinterpret_cast<const float4*>(x + (size_t)t * DIM);
  ushort4* xo = reinterpret_cast<ushort4*>(xb + (size_t)t * DIM);
  float acc[NEXP];
#pragma unroll
  for (int e = 0; e < NEXP; ++e) acc[e] = 0.f;
#pragma unroll
  for (int j = 0; j < DIM / 4 / 64; ++j) {     // 8 iters
    float4 xv = xr[lane + 64 * j];
    union { ushort4 u; __hip_bfloat16 h[4]; } cv;
    cv.h[0] = __float2bfloat16(xv.x);
    cv.h[1] = __float2bfloat16(xv.y);
    cv.h[2] = __float2bfloat16(xv.z);
    cv.h[3] = __float2bfloat16(xv.w);
    xo[lane + 64 * j] = cv.u;                  // fused x -> bf16 cast
#pragma unroll
    for (int e = 0; e < NEXP; ++e) {
      float4 gv = reinterpret_cast<const float4*>(wg + (size_t)e * DIM)[lane + 64 * j];
      acc[e] += xv.x * gv.x + xv.y * gv.y + xv.z * gv.z + xv.w * gv.w;
    }
  }
#pragma unroll
  for (int e = 0; e < NEXP; ++e) {
    float v = acc[e];
#pragma unroll
    for (int off = 32; off > 0; off >>= 1) v += __shfl_down(v, off);
    acc[e] = v;
  }
  if (lane == 0) {
    float lg[NEXP];
#pragma unroll
    for (int e = 0; e < NEXP; ++e) lg[e] = acc[e] + bg[e];
    float m = lg[0];
#pragma unroll
    for (int e = 1; e < NEXP; ++e) m = fmaxf(m, lg[e]);
    float s = 0.f, w[NEXP];
#pragma unroll
    for (int e = 0; e < NEXP; ++e) { w[e] = expf(lg[e] - m); s += w[e]; }
    float inv = 1.f / s;
    int i0 = 0;
#pragma unroll
    for (int e = 1; e < NEXP; ++e) if (lg[e] > lg[i0]) i0 = e;
    int i1 = -1;
#pragma unroll
    for (int e = 0; e < NEXP; ++e)
      if (e != i0 && (i1 < 0 || lg[e] > lg[i1])) i1 = e;
    int p0 = atomicAdd(&cnt[i0], 1);
    toklist[i0 * N_TOK + p0] = t;  wlist[i0 * N_TOK + p0] = w[i0] * inv;
    int p1 = atomicAdd(&cnt[i1], 1);
    toklist[i1 * N_TOK + p1] = t;  wlist[i1 * N_TOK + p1] = w[i1] * inv;
  }
}

// ---------------- grouped GEMM: C = relu(Xg @ We^T + be) * wt, atomicAdd to out ----
// 2048 blocks (8 experts x 32 row-slots x 8 col-tiles), 512 threads = 8 waves (2Mx4N).
// 256x256 tile, BK=64, double-buffered 2-phase: stage(next) -> compute(cur) -> barrier.
// XCD-chunked swizzle: expert e lands on XCD e (W + X panels stay in one L2).
__global__ __launch_bounds__(512, 2) void moe_gemm(
    const __hip_bfloat16* __restrict__ xb, const __hip_bfloat16* __restrict__ wb,
    const float* __restrict__ be, const int* __restrict__ cnt,
    const int* __restrict__ toklist, const float* __restrict__ wlist,
    float* __restrict__ out) {
  const int p = blockIdx.x;                 // 0..2047
  const int l = (p & 7) * 256 + (p >> 3);   // bijective XCD-chunked remap
  const int e  = l >> 8;
  const int ct = (l >> 5) & 7;
  const int tr = l & 31;
  const int ce = cnt[e];
  const int row0 = tr * BM;
  if (row0 >= ce) return;                   // uniform early-exit
  const int bn0 = ct * BN;

  __shared__ __align__(16) __hip_bfloat16 sA[2][BM * BK];  // 2 x 32 KB
  __shared__ __align__(16) __hip_bfloat16 sB[2][BN * BK];  // 2 x 32 KB
  __shared__ int   sTok[BM];
  __shared__ float sWt[BM];

  const int tid = threadIdx.x;
  if (tid < BM) {
    int r = row0 + tid;
    bool valid = r < ce;
    sTok[tid] = valid ? toklist[e * N_TOK + r] : 0;
    sWt[tid]  = valid ? wlist[e * N_TOK + r] : 0.f;
  }
  __syncthreads();

  // Staging sources. LDS dest LINEAR (global_load_lds rule); XOR granule swizzle
  // (g = p ^ (r&7), 16B granules in 128B rows) applied on the GLOBAL source; reads
  // apply the same XOR (involution, verified r1: absmax pass, 0 bank conflicts).
  const char* srcA[4];
  const char* srcB[4];
#pragma unroll
  for (int n = 0; n < 4; ++n) {
    int c = tid + 512 * n;    // 16B chunk id 0..2047
    int r = c >> 3;           // tile row 0..255
    int pg = c & 7;           // physical granule
    int g = pg ^ (r & 7);     // logical (source) granule
    srcA[n] = (const char*)(xb + (size_t)sTok[r] * DIM + g * 8);
    srcB[n] = (const char*)(wb + (size_t)(e * DIM + bn0 + r) * DIM + g * 8);
  }

  const int lane = tid & 63;
  const int wv = tid >> 6;
  const int wr = (wv >> 2) * 128;   // wave row offset (2 M-waves)
  const int wc = (wv & 3) * 64;     // wave col offset (4 N-waves)

  f32x4 acc[8][4];
#pragma unroll
  for (int mi = 0; mi < 8; ++mi)
#pragma unroll
    for (int ni = 0; ni < 4; ++ni)
      acc[mi][ni] = (f32x4){0.f, 0.f, 0.f, 0.f};

  auto stage = [&](int buf, int kt) {
    const int koff = kt * (BK * 2);   // bytes along K
#pragma unroll
    for (int n = 0; n < 4; ++n) {
      gload_lds16(srcA[n] + koff, (char*)sA[buf] + (tid + 512 * n) * 16);
      gload_lds16(srcB[n] + koff, (char*)sB[buf] + (tid + 512 * n) * 16);
    }
  };

  // prologue: stage K-tile 0 into buf0; __syncthreads drains vmcnt
  stage(0, 0);
  __syncthreads();

  int cur = 0;
  for (int kt = 0; kt < KT; ++kt) {
    if (kt + 1 < KT) stage(cur ^ 1, kt + 1);   // issue next-tile loads FIRST
    // compute current buffer
#pragma unroll
    for (int ks = 0; ks < 2; ++ks) {
      const int gbase = ks * 4 + (lane >> 4);
      short8 bfr[4];
#pragma unroll
      for (int i = 0; i < 4; ++i) {
        int rB = wc + i * 16 + (lane & 15);
        bfr[i] = *(const short8*)((const char*)sB[cur] + rB * 128 +
                                  ((gbase ^ (rB & 7)) << 4));
      }
#pragma unroll
      for (int mi = 0; mi < 8; ++mi) {
        int rA = wr + mi * 16 + (lane & 15);
        short8 a = *(const short8*)((const char*)sA[cur] + rA * 128 +
                                    ((gbase ^ (rA & 7)) << 4));
#pragma unroll
        for (int ni = 0; ni < 4; ++ni)
          acc[mi][ni] = __builtin_amdgcn_mfma_f32_16x16x32_bf16(
              a, bfr[ni], acc[mi][ni], 0, 0, 0);
      }
    }
    __syncthreads();   // drains vmcnt(0): staged loads landed; all waves done reading
    cur ^= 1;
  }

  // epilogue: bias + relu + gate-weight, accumulate into out (pre-zeroed).
  // C/D layout (m89-verified): col = lane&15, row = (lane>>4)*4 + reg.
  const int cvalid = ce - row0;
#pragma unroll
  for (int mi = 0; mi < 8; ++mi) {
    int lr0 = wr + mi * 16 + (lane >> 4) * 4;
#pragma unroll
    for (int ni = 0; ni < 4; ++ni) {
      int col = bn0 + wc + ni * 16 + (lane & 15);
      float bv = be[e * DIM + col];
#pragma unroll
      for (int q = 0; q < 4; ++q) {
        int lr = lr0 + q;
        if (lr < cvalid) {
          float v = fmaxf(acc[mi][ni][q] + bv, 0.f) * sWt[lr];
          atomicAdd(out + (size_t)sTok[lr] * DIM + col, v);
        }
      }
    }
  }
}

extern "C" void kernel_launch(void* const* d_in, const int* in_sizes, int n_in,
                              void* d_out, int out_size, void* d_ws, size_t ws_size,
                              hipStream_t stream) {
  const float* x  = (const float*)d_in[0];
  const float* We = (const float*)d_in[1];
  const float* be = (const float*)d_in[2];
  const float* Wg = (const float*)d_in[3];
  const float* bg = (const float*)d_in[4];
  float* out = (float*)d_out;
  char* ws = (char*)d_ws;

  int*   cnt = (int*)(ws + OFF_CNT);
  int*   tok = (int*)(ws + OFF_TOK);
  float* wl  = (float*)(ws + OFF_WL);
  __hip_bfloat16* xb = (__hip_bfloat16*)(ws + OFF_XB);
  __hip_bfloat16* wb = (__hip_bfloat16*)(ws + OFF_WB);

  hipMemsetAsync(cnt, 0, 1024, stream);
  hipMemsetAsync(out, 0, (size_t)N_TOK * DIM * sizeof(float), stream);

  gate_kernel<<<N_TOK / 4, 256, 0, stream>>>(x, Wg, bg, xb, cnt, tok, wl);
  cvt_kernel<<<2048, 256, 0, stream>>>(We, wb, NEXP * DIM * DIM / 4);

  moe_gemm<<<2048, 512, 0, stream>>>(xb, wb, be, cnt, tok, wl, out);
}